// Round 13
// baseline (300.419 us; speedup 1.0000x reference)
//
#include <hip/hip_runtime.h>

typedef __attribute__((ext_vector_type(4))) float f32x4;
typedef __attribute__((ext_vector_type(8))) __bf16 bf16x8;
typedef unsigned short u16;

#define GAS(p) ((const __attribute__((address_space(1))) void*)(p))
#define LAS(p) ((__attribute__((address_space(3))) void*)(p))

__device__ __forceinline__ u16 f32_to_bf16(float f) {
  unsigned u = __builtin_bit_cast(unsigned, f);
  u += 0x7FFFu + ((u >> 16) & 1u);
  return (u16)(u >> 16);
}

// ---------------- elementwise f32 -> bf16 ----------------
__global__ __launch_bounds__(256) void k_convert(const float* __restrict__ X,
                                                 u16* __restrict__ Y, int n4) {
  int i = blockIdx.x * 256 + threadIdx.x;
  if (i >= n4) return;
  float4 v = ((const float4*)X)[i];
  ushort4 r;
  r.x = f32_to_bf16(v.x); r.y = f32_to_bf16(v.y);
  r.z = f32_to_bf16(v.z); r.w = f32_to_bf16(v.w);
  ((ushort4*)Y)[i] = r;
}

// ---------------- W [K][N] f32 -> WT [N][K] bf16 ----------------
__global__ __launch_bounds__(256) void k_transpose_w(const float* __restrict__ W,
                                                     u16* __restrict__ WT,
                                                     int K, int N) {
  __shared__ float tile[32][33];
  int n0 = blockIdx.x * 32, k0 = blockIdx.y * 32;
  int tx = threadIdx.x & 31, ty = threadIdx.x >> 5;
#pragma unroll
  for (int r = 0; r < 4; ++r)
    tile[ty + r * 8][tx] = W[(long)(k0 + ty + r * 8) * N + n0 + tx];
  __syncthreads();
#pragma unroll
  for (int r = 0; r < 4; ++r)
    WT[(long)(n0 + ty + r * 8) * K + k0 + tx] = f32_to_bf16(tile[tx][ty + r * 8]);
}

// ---------------- V [BH][S][128] bf16 -> VT [BH][128][S] bf16 ----------------
__global__ __launch_bounds__(256) void k_transpose_v(const u16* __restrict__ V,
                                                     u16* __restrict__ VT) {
  __shared__ u16 tile[32][34];
  int s0 = blockIdx.x * 32, d0 = blockIdx.y * 32, bh = blockIdx.z;
  int tx = threadIdx.x & 31, ty = threadIdx.x >> 5;
  const u16* Vb = V + (long)bh * 2048 * 128;
  u16* VTb = VT + (long)bh * 128 * 2048;
#pragma unroll
  for (int r = 0; r < 4; ++r)
    tile[ty + r * 8][tx] = Vb[(long)(s0 + ty + r * 8) * 128 + d0 + tx];
  __syncthreads();
#pragma unroll
  for (int r = 0; r < 4; ++r)
    VTb[(long)(d0 + ty + r * 8) * 2048 + s0 + tx] = tile[tx][ty + r * 8];
}

// ===== 256x256 8-phase bf16 GEMM, BK=64, DEEP PREFETCH (R13) =====
// R12 post-mortem: R11/R12 staged tile t+1 spread across tile t's phases,
// giving B only 1-2 phases (~150-300 cy) of lead before its vmcnt — every
// tile stalled on L2/HBM latency at the wait. Fix: issue ALL 8 loads of
// tile t+1 at p0 of tile t (B rows 0..255 first, then A in first-read
// order ld0(r0-63), ld2(r128-191), ld1(r64-127), ld3(r192-255)), giving
// every load 3-5 phases (~450-750 cy) of lead.  Counted waits (per-wave
// vmcnt, in-order retirement):
//   p1: vmcnt(8)  [outstanding = A-ld1,ld3(t):2 + stage8(t+1):8 -> confirms
//                  ld1,ld3(t), issued 4+ phases earlier]
//   p3: vmcnt(2)  [confirms B x4 + A-ld0,ld2 of (t+1); ld1,ld3(t+1) fly on]
// Never drain-0 mid-loop. Phase p reads A rows wr*128 + p*32..p*32+31:
// phases 0-1 -> ld0/ld2, phases 2-3 -> ld1/ld3 (matches the wait sets).
// Race rule (R11, proven): every cross-wave read follows {issuer vmcnt ->
// s_barrier}; buffer overwrite only after the end-of-tile barrier that all
// readers passed post-consumption.  T2 chunk-XOR swizzle; T5 setprio.
template <int EPI>
__global__ __launch_bounds__(512, 2) void k_gemm256(
    const u16* __restrict__ A, const u16* __restrict__ BT,
    const float* __restrict__ bias,
    u16* __restrict__ Qo, u16* __restrict__ Ko, u16* __restrict__ Vo,
    float* __restrict__ Cout, int M, int N, int K) {
  __shared__ alignas(16) u16 AS[2][256 * 64];  // 2 x 32 KB
  __shared__ alignas(16) u16 BS[2][256 * 64];  // 2 x 32 KB
  const int wave = threadIdx.x >> 6, lane = threadIdx.x & 63;
  const int wr = wave >> 2, wc = wave & 3;
  const int l15 = lane & 15, l4 = lane >> 4;
  const int sl = lane & 7, sr = (lane >> 3) & 7;

  const int nwg = gridDim.x;  // % 8 == 0
  const int swz = ((int)blockIdx.x & 7) * (nwg >> 3) + ((int)blockIdx.x >> 3);
  const int mt = M >> 8;
  const int bm = swz % mt, bn = swz / mt;
  const int brow = bm * 256, bcol = bn * 256;
  const int NT = K >> 6;  // 32 (even; loop unrolled by 2)

  const u16* aBase = A + (long)(brow + wave * 8 + sr) * K + (sl ^ sr) * 8;
  const u16* bBase = BT + (long)(bcol + wave * 8 + sr) * K + (sl ^ sr) * 8;
  const long K64 = (long)K * 64;

  auto ld = [&](const u16* g, u16* l) {
    __builtin_amdgcn_global_load_lds(GAS(g), LAS(l + wave * 512), 16, 0, 0);
  };
  // Entire tile in one burst; issue order = confirmation order:
  // B(4), A-ld0, A-ld2  <- confirmed by p3's vmcnt(2)
  // A-ld1, A-ld3        <- confirmed by next tile's p1 vmcnt(8)
  auto stage8 = [&](long t64, int buf) {
    ld(bBase + t64, &BS[buf][0]);
    ld(bBase + t64 + K64, &BS[buf][64 * 64]);
    ld(bBase + t64 + 2 * K64, &BS[buf][128 * 64]);
    ld(bBase + t64 + 3 * K64, &BS[buf][192 * 64]);
    ld(aBase + t64, &AS[buf][0]);            // ld0: rows 0-63
    ld(aBase + t64 + 2 * K64, &AS[buf][128 * 64]);  // ld2: rows 128-191
    ld(aBase + t64 + K64, &AS[buf][64 * 64]);       // ld1: rows 64-127
    ld(aBase + t64 + 3 * K64, &AS[buf][192 * 64]);  // ld3: rows 192-255
  };

  const f32x4 fzero = {0.f, 0.f, 0.f, 0.f};
  f32x4 acc[8][4];
#pragma unroll
  for (int m = 0; m < 8; ++m)
#pragma unroll
    for (int n = 0; n < 4; ++n) acc[m][n] = fzero;

  bf16x8 bfA[4][2], bfB[4][2], afA[2][2], afB[2][2];

#define BAR()                      \
  __builtin_amdgcn_s_barrier();    \
  asm volatile("" ::: "memory")

#define RD_A(DST, P, BUF)                                                   \
  do {                                                                      \
    _Pragma("unroll") for (int mm = 0; mm < 2; ++mm)                        \
        _Pragma("unroll") for (int kk = 0; kk < 2; ++kk) {                  \
      const int R = wr * 128 + ((P) * 2 + mm) * 16 + l15;                   \
      DST[mm][kk] = *(const bf16x8*)(&AS[BUF][R * 64 +                      \
                                             (((kk * 4 + l4) ^ (l15 & 7)) * 8)]); \
    }                                                                       \
  } while (0)

#define RD_B(DST, BUF)                                                      \
  do {                                                                      \
    _Pragma("unroll") for (int n = 0; n < 4; ++n)                           \
        _Pragma("unroll") for (int kk = 0; kk < 2; ++kk) {                  \
      const int R = wc * 64 + n * 16 + l15;                                 \
      DST[n][kk] = *(const bf16x8*)(&BS[BUF][R * 64 +                       \
                                            (((kk * 4 + l4) ^ (l15 & 7)) * 8)]); \
    }                                                                       \
  } while (0)

#define MM(P, AF, BF)                                                       \
  do {                                                                      \
    __builtin_amdgcn_s_setprio(1);                                          \
    _Pragma("unroll") for (int mm = 0; mm < 2; ++mm)                        \
        _Pragma("unroll") for (int n = 0; n < 4; ++n)                       \
            _Pragma("unroll") for (int kk = 0; kk < 2; ++kk)                \
                acc[(P) * 2 + mm][n] = __builtin_amdgcn_mfma_f32_16x16x32_bf16( \
                    AF[mm][kk], BF[n][kk], acc[(P) * 2 + mm][n], 0, 0, 0);  \
    __builtin_amdgcn_s_setprio(0);                                          \
  } while (0)

#define TILE(T, CUR, NXT, BFC, BFN)                                         \
  do {                                                                      \
    const bool pre = ((T) + 1 < NT);                                        \
    const long n64 = (long)((T) + 1) * 64;                                  \
    /* p0: burst-stage ALL of tile t+1 */                                   \
    if (pre) stage8(n64, NXT);                                              \
    RD_A(afB, 1, CUR);                                                      \
    MM(0, afA, BFC);                                                        \
    BAR();                                                                  \
    /* p1: confirm A-ld1,ld3(t), issued 4+ phases ago */                    \
    if (pre)                                                                \
      asm volatile("s_waitcnt vmcnt(8)" ::: "memory");                      \
    else                                                                    \
      asm volatile("s_waitcnt vmcnt(0)" ::: "memory");                      \
    BAR();                                                                  \
    RD_A(afA, 2, CUR);                                                      \
    MM(1, afB, BFC);                                                        \
    BAR();                                                                  \
    /* p2 */                                                                \
    RD_A(afB, 3, CUR);                                                      \
    MM(2, afA, BFC);                                                        \
    BAR();                                                                  \
    /* p3: confirm B + A-ld0,ld2 of t+1 (3 phases lead); preload t+1 */     \
    if (pre) asm volatile("s_waitcnt vmcnt(2)" ::: "memory");               \
    BAR();                                                                  \
    if (pre) {                                                              \
      RD_B(BFN, NXT);                                                       \
      RD_A(afA, 0, NXT);                                                    \
    }                                                                       \
    MM(3, afB, BFC);                                                        \
    BAR();                                                                  \
  } while (0)

  // prologue: tile 0 staged + drained; preload bfr/afr0 of tile 0
  stage8(0, 0);
  asm volatile("s_waitcnt vmcnt(0)" ::: "memory");
  BAR();
  RD_B(bfA, 0);
  RD_A(afA, 0, 0);

  for (int tp = 0; tp < NT; tp += 2) {
    TILE(tp, 0, 1, bfA, bfB);
    TILE(tp + 1, 1, 0, bfB, bfA);
  }
#undef TILE
#undef MM
#undef RD_B
#undef RD_A
#undef BAR

  if (EPI == 0) {
#pragma unroll
    for (int n = 0; n < 4; ++n) {
      const int col = bcol + wc * 64 + n * 16 + l15;
      const int which = col >> 11;
      u16* dst = (which == 0) ? Qo : (which == 1) ? Ko : Vo;
      const int cc = col & 2047;
      const int h = cc >> 7, d = cc & 127;
      const float bv = bias[col];
#pragma unroll
      for (int m = 0; m < 8; ++m) {
#pragma unroll
        for (int r = 0; r < 4; ++r) {
          const int row = brow + wr * 128 + m * 16 + l4 * 4 + r;  // b*2048+s
          const int bb = row >> 11, s = row & 2047;
          dst[(((long)(bb * 16 + h)) * 2048 + s) * 128 + d] =
              f32_to_bf16(acc[m][n][r] + bv);
        }
      }
    }
  } else {
#pragma unroll
    for (int m = 0; m < 8; ++m)
#pragma unroll
      for (int r = 0; r < 4; ++r) {
        const int row = brow + wr * 128 + m * 16 + l4 * 4 + r;
#pragma unroll
        for (int n = 0; n < 4; ++n) {
          const int col = bcol + wc * 64 + n * 16 + l15;
          Cout[(long)row * N + col] = acc[m][n][r] + bias[col];
        }
      }
  }
}

// ===== 128x256 bf16 GEMM, BK=64, 3 LDS buffers (R10, proven) =====
// Used for GEMM2: grid 256 = 1/CU exact.
template <int EPI>
__global__ __launch_bounds__(512, 2) void k_gemm(
    const u16* __restrict__ A, const u16* __restrict__ BT,
    const float* __restrict__ bias,
    u16* __restrict__ Qo, u16* __restrict__ Ko, u16* __restrict__ Vo,
    float* __restrict__ Cout, int M, int N, int K) {
  __shared__ alignas(16) u16 AS[3][128 * 64];
  __shared__ alignas(16) u16 BS[3][256 * 64];
  const int wave = threadIdx.x >> 6, lane = threadIdx.x & 63;
  const int wr = wave >> 2, wc = wave & 3;
  const int l15 = lane & 15, l4 = lane >> 4;
  const int sl = lane & 7, sr = (lane >> 3) & 7;

  const int nwg = gridDim.x;
  const int swz = ((int)blockIdx.x & 7) * (nwg >> 3) + ((int)blockIdx.x >> 3);
  const int mt = M >> 7;
  const int bm = swz % mt, bn = swz / mt;
  const int brow = bm * 128, bcol = bn * 256;
  const int NT = K >> 6;

  const u16* aBase = A + (long)(brow + wave * 8 + sr) * K + (sl ^ sr) * 8;
  const u16* bBase = BT + (long)(bcol + wave * 8 + sr) * K + (sl ^ sr) * 8;
  const long K64 = (long)K * 64;

  auto stage = [&](int t, int buf) {
    const long t64 = (long)t * 64;
#pragma unroll
    for (int j = 0; j < 2; ++j)
      __builtin_amdgcn_global_load_lds(GAS(aBase + t64 + j * K64),
                                       LAS(&AS[buf][(wave + j * 8) * 512]), 16, 0, 0);
#pragma unroll
    for (int j = 0; j < 4; ++j)
      __builtin_amdgcn_global_load_lds(GAS(bBase + t64 + j * K64),
                                       LAS(&BS[buf][(wave + j * 8) * 512]), 16, 0, 0);
  };

  const f32x4 fzero = {0.f, 0.f, 0.f, 0.f};
  f32x4 acc[4][4];
#pragma unroll
  for (int m = 0; m < 4; ++m)
#pragma unroll
    for (int n = 0; n < 4; ++n) acc[m][n] = fzero;

  auto compute = [&](int buf) {
    const u16* Ac = &AS[buf][0];
    const u16* Bc = &BS[buf][0];
    bf16x8 afr[4][2], bfr[4][2];
#pragma unroll
    for (int f = 0; f < 4; ++f)
#pragma unroll
      for (int kk = 0; kk < 2; ++kk) {
        const int Ra = wr * 64 + f * 16 + l15;
        afr[f][kk] =
            *(const bf16x8*)(Ac + Ra * 64 + (((kk * 4 + l4) ^ (l15 & 7)) * 8));
        const int Rb = wc * 64 + f * 16 + l15;
        bfr[f][kk] =
            *(const bf16x8*)(Bc + Rb * 64 + (((kk * 4 + l4) ^ (l15 & 7)) * 8));
      }
    __builtin_amdgcn_s_setprio(1);
#pragma unroll
    for (int m = 0; m < 4; ++m)
#pragma unroll
      for (int n = 0; n < 4; ++n)
#pragma unroll
        for (int kk = 0; kk < 2; ++kk)
          acc[m][n] = __builtin_amdgcn_mfma_f32_16x16x32_bf16(
              afr[m][kk], bfr[n][kk], acc[m][n], 0, 0, 0);
    __builtin_amdgcn_s_setprio(0);
  };

  stage(0, 0);
  stage(1, 1);
  int bufc = 0;
  for (int t = 0; t < NT - 1; ++t) {
    asm volatile("s_waitcnt vmcnt(6)" ::: "memory");
    __builtin_amdgcn_s_barrier();
    if (t + 2 < NT) {
      int bufn = bufc + 2;
      if (bufn >= 3) bufn -= 3;
      stage(t + 2, bufn);
    }
    compute(bufc);
    ++bufc;
    if (bufc == 3) bufc = 0;
  }
  asm volatile("s_waitcnt vmcnt(0)" ::: "memory");
  __builtin_amdgcn_s_barrier();
  compute(bufc);

  if (EPI == 0) {
#pragma unroll
    for (int n = 0; n < 4; ++n) {
      const int col = bcol + wc * 64 + n * 16 + l15;
      const int which = col >> 11;
      u16* dst = (which == 0) ? Qo : (which == 1) ? Ko : Vo;
      const int cc = col & 2047;
      const int h = cc >> 7, d = cc & 127;
      const float bv = bias[col];
#pragma unroll
      for (int m = 0; m < 4; ++m) {
#pragma unroll
        for (int r = 0; r < 4; ++r) {
          const int row = brow + wr * 64 + m * 16 + l4 * 4 + r;
          const int bb = row >> 11, s = row & 2047;
          dst[(((long)(bb * 16 + h)) * 2048 + s) * 128 + d] =
              f32_to_bf16(acc[m][n][r] + bv);
        }
      }
    }
  } else {
#pragma unroll
    for (int m = 0; m < 4; ++m)
#pragma unroll
      for (int r = 0; r < 4; ++r) {
        const int row = brow + wr * 64 + m * 16 + l4 * 4 + r;
#pragma unroll
        for (int n = 0; n < 4; ++n) {
          const int col = bcol + wc * 64 + n * 16 + l15;
          Cout[(long)row * N + col] = acc[m][n][r] + bias[col];
        }
      }
  }
}

// ---------------- flash attention with ALiBi, causal ----------------
// (unchanged from R7 — verified; LDS-staged K/V^T, double-buffered, swizzled)
__global__ __launch_bounds__(256, 4) void k_attn(const u16* __restrict__ Q,
                                                 const u16* __restrict__ Kp,
                                                 const u16* __restrict__ VT,
                                                 u16* __restrict__ Oa) {
  __shared__ alignas(16) u16 Kl[2][64 * 128];
  __shared__ alignas(16) u16 Vl[2][128 * 64];
  __shared__ alignas(16) u16 Pl[4][16 * 64];
  const int b = blockIdx.x;
  const int bh = b & 31;
  const int qt = 31 - (b >> 5);  // heavy-first
  const int bb = bh >> 4, h = bh & 15;
  const int wave = threadIdx.x >> 6, lane = threadIdx.x & 63;
  const int l15 = lane & 15, l4 = lane >> 4;
  const int l7 = lane & 7, l8 = lane >> 3;
  const float LOG2E = 1.4426950408889634f;
  const float scale = 0.08838834764831845f * LOG2E;
  const float slope = exp2f(-0.5f * (float)h) * LOG2E;

  const int q0 = qt * 64 + wave * 16;
  const u16* Qb = Q + ((long)bh * 2048 + q0 + l15) * 128;
  bf16x8 qf[4];
#pragma unroll
  for (int kk = 0; kk < 4; ++kk) qf[kk] = *(const bf16x8*)(Qb + kk * 32 + l4 * 8);

  const u16* Kb = Kp + (long)bh * 2048 * 128;
  const u16* VTb = VT + (long)bh * 128 * 2048;

  auto stageK = [&](int jt, int buf) {
#pragma unroll
    for (int g = 0; g < 4; ++g) {
      const int wcc = g * 4 + wave;
      const int row = wcc * 4 + l4;
      const u16* src = Kb + (long)(jt * 64 + row) * 128 + ((l15 ^ (row & 7)) * 8);
      __builtin_amdgcn_global_load_lds(GAS(src), LAS(&Kl[buf][wcc * 512]), 16, 0, 0);
    }
  };
  auto stageV = [&](int jt, int buf) {
#pragma unroll
    for (int g = 0; g < 4; ++g) {
      const int wcc = g * 4 + wave;
      const int d = wcc * 8 + l8;
      const u16* src = VTb + (long)d * 2048 + jt * 64 + ((l7 ^ l8) * 8);
      __builtin_amdgcn_global_load_lds(GAS(src), LAS(&Vl[buf][wcc * 512]), 16, 0, 0);
    }
  };

  float rs[4];
  f32x4 O[8];
  const f32x4 fzero = {0.f, 0.f, 0.f, 0.f};
#pragma unroll
  for (int r = 0; r < 4; ++r) rs[r] = 0.f;
#pragma unroll
  for (int nb = 0; nb < 8; ++nb) O[nb] = fzero;

  u16* Pw = Pl[wave];
  const int irow = q0 + l4 * 4;
  const int sw = l15 & 7;

  stageK(0, 0);
  stageV(0, 0);
  __syncthreads();

  for (int jt = 0; jt <= qt; ++jt) {
    const int cur = jt & 1;
    if (jt < qt) {
      stageK(jt + 1, cur ^ 1);
      stageV(jt + 1, cur ^ 1);
    }
    const u16* Kc = Kl[cur];
    const u16* Vc = Vl[cur];
    const int j0 = jt * 64;
#pragma unroll
    for (int cb = 0; cb < 4; ++cb) {
      f32x4 sa = fzero;
      const u16* kp = Kc + (cb * 16 + l15) * 128;
#pragma unroll
      for (int kk = 0; kk < 4; ++kk) {
        bf16x8 kf = *(const bf16x8*)(kp + (((kk * 4 + l4) ^ sw) * 8));
        sa = __builtin_amdgcn_mfma_f32_16x16x32_bf16(qf[kk], kf, sa, 0, 0, 0);
      }
      const int j = j0 + cb * 16 + l15;
#pragma unroll
      for (int r = 0; r < 4; ++r) {
        int i = irow + r;
        float s = sa[r] * scale - slope * (float)(i - j);
        float p = __builtin_amdgcn_exp2f((j <= i) ? s : -1e30f);
        rs[r] += p;
        int rloc = l4 * 4 + r;
        int cbyte = (cb * 16 + l15) * 2;
        *(u16*)((char*)Pw + rloc * 128 + (cbyte ^ ((rloc & 7) << 4))) =
            f32_to_bf16(p);
      }
    }
    bf16x8 pf0 = *(const bf16x8*)((char*)Pw + l15 * 128 +
                                  ((l4 * 16) ^ ((l15 & 7) << 4)));
    bf16x8 pf1 = *(const bf16x8*)((char*)Pw + l15 * 128 +
                                  ((64 + l4 * 16) ^ ((l15 & 7) << 4)));
#pragma unroll
    for (int nb = 0; nb < 8; ++nb) {
      const u16* vp = Vc + (nb * 16 + l15) * 64;
      bf16x8 v0 = *(const bf16x8*)(vp + ((l4 ^ sw) * 8));
      bf16x8 v1 = *(const bf16x8*)(vp + (((4 + l4) ^ sw) * 8));
      O[nb] = __builtin_amdgcn_mfma_f32_16x16x32_bf16(pf0, v0, O[nb], 0, 0, 0);
      O[nb] = __builtin_amdgcn_mfma_f32_16x16x32_bf16(pf1, v1, O[nb], 0, 0, 0);
    }
    __syncthreads();
  }
#pragma unroll
  for (int r = 0; r < 4; ++r) {
    float v = rs[r];
    v += __shfl_xor(v, 1);
    v += __shfl_xor(v, 2);
    v += __shfl_xor(v, 4);
    v += __shfl_xor(v, 8);
    float inv = 1.f / v;
    int i = irow + r;
    u16* op = Oa + ((long)bb * 2048 + i) * 2048 + h * 128;
#pragma unroll
    for (int nb = 0; nb < 8; ++nb) op[nb * 16 + l15] = f32_to_bf16(O[nb][r] * inv);
  }
}

extern "C" void kernel_launch(void* const* d_in, const int* in_sizes, int n_in,
                              void* d_out, int out_size, void* d_ws, size_t ws_size,
                              hipStream_t stream) {
  const float* x = (const float*)d_in[0];
  const float* Wqkv = (const float*)d_in[1];
  const float* bqkv = (const float*)d_in[2];
  const float* Wo = (const float*)d_in[3];
  const float* bo = (const float*)d_in[4];
  float* out = (float*)d_out;

  char* ws = (char*)d_ws;
  u16* xb = (u16*)(ws);
  u16* VTb = (u16*)(ws);  // aliases xb (xb dead after GEMM1)
  u16* WqkvT = (u16*)(ws + 16777216);
  u16* attn_out = (u16*)(ws + 16777216);  // aliases WqkvT (dead after GEMM1)
  u16* WoT = (u16*)(ws + 16777216 + 25165824);
  u16* Qb = (u16*)(ws + 50331648);
  u16* Kb = (u16*)(ws + 67108864);
  u16* Vb = (u16*)(ws + 83886080);

  k_convert<<<8192, 256, 0, stream>>>(x, xb, 8388608 / 4);
  k_transpose_w<<<dim3(192, 64), 256, 0, stream>>>(Wqkv, WqkvT, 2048, 6144);
  k_transpose_w<<<dim3(64, 64), 256, 0, stream>>>(Wo, WoT, 2048, 2048);
  // GEMM1: 256^2 tiles -> 16 x 24 = 384 blocks (1.5 rounds; deep prefetch)
  k_gemm256<0><<<dim3(384), 512, 0, stream>>>(xb, WqkvT, bqkv, Qb, Kb, Vb,
                                              nullptr, 4096, 6144, 2048);
  k_transpose_v<<<dim3(64, 4, 32), 256, 0, stream>>>(Vb, VTb);
  k_attn<<<dim3(1024), 256, 0, stream>>>(Qb, Kb, VTb, attn_out);
  // GEMM2: 128x256 tiles -> 32 x 8 = 256 blocks = 1/CU exact
  k_gemm<1><<<dim3(256), 512, 0, stream>>>(attn_out, WoT, bo, nullptr,
                                           nullptr, nullptr, out, 4096, 2048,
                                           2048);
}

// Round 14
// 275.177 us; speedup vs baseline: 1.0917x; 1.0917x over previous
//
#include <hip/hip_runtime.h>

typedef __attribute__((ext_vector_type(4))) float f32x4;
typedef __attribute__((ext_vector_type(8))) __bf16 bf16x8;
typedef unsigned short u16;

#define GAS(p) ((const __attribute__((address_space(1))) void*)(p))
#define LAS(p) ((__attribute__((address_space(3))) void*)(p))

__device__ __forceinline__ u16 f32_to_bf16(float f) {
  unsigned u = __builtin_bit_cast(unsigned, f);
  u += 0x7FFFu + ((u >> 16) & 1u);
  return (u16)(u >> 16);
}

// ---------------- elementwise f32 -> bf16 ----------------
__global__ __launch_bounds__(256) void k_convert(const float* __restrict__ X,
                                                 u16* __restrict__ Y, int n4) {
  int i = blockIdx.x * 256 + threadIdx.x;
  if (i >= n4) return;
  float4 v = ((const float4*)X)[i];
  ushort4 r;
  r.x = f32_to_bf16(v.x); r.y = f32_to_bf16(v.y);
  r.z = f32_to_bf16(v.z); r.w = f32_to_bf16(v.w);
  ((ushort4*)Y)[i] = r;
}

// ---------------- W [K][N] f32 -> WT [N][K] bf16 ----------------
__global__ __launch_bounds__(256) void k_transpose_w(const float* __restrict__ W,
                                                     u16* __restrict__ WT,
                                                     int K, int N) {
  __shared__ float tile[32][33];
  int n0 = blockIdx.x * 32, k0 = blockIdx.y * 32;
  int tx = threadIdx.x & 31, ty = threadIdx.x >> 5;
#pragma unroll
  for (int r = 0; r < 4; ++r)
    tile[ty + r * 8][tx] = W[(long)(k0 + ty + r * 8) * N + n0 + tx];
  __syncthreads();
#pragma unroll
  for (int r = 0; r < 4; ++r)
    WT[(long)(n0 + ty + r * 8) * K + k0 + tx] = f32_to_bf16(tile[tx][ty + r * 8]);
}

// ---------------- V [BH][S][128] bf16 -> VT [BH][128][S] bf16 ----------------
__global__ __launch_bounds__(256) void k_transpose_v(const u16* __restrict__ V,
                                                     u16* __restrict__ VT) {
  __shared__ u16 tile[32][34];
  int s0 = blockIdx.x * 32, d0 = blockIdx.y * 32, bh = blockIdx.z;
  int tx = threadIdx.x & 31, ty = threadIdx.x >> 5;
  const u16* Vb = V + (long)bh * 2048 * 128;
  u16* VTb = VT + (long)bh * 128 * 2048;
#pragma unroll
  for (int r = 0; r < 4; ++r)
    tile[ty + r * 8][tx] = Vb[(long)(s0 + ty + r * 8) * 128 + d0 + tx];
  __syncthreads();
#pragma unroll
  for (int r = 0; r < 4; ++r)
    VTb[(long)(d0 + ty + r * 8) * 2048 + s0 + tx] = tile[tx][ty + r * 8];
}

// ===== 128x128 bf16 GEMM, BK=32, 3 LDS buffers, 4 waves, 3 BLOCKS/CU =====
// R13 post-mortem: every 1-block/CU config (2-phase or 8-phase) plateaus at
// 589-830 TF active — with a single resident block, all waves drain at the
// same barrier and nothing covers the stall (m233: stage+vmcnt+barrier =
// ~72% of 2-phase time). m97/m103's 912 TF used 128^2/BK=32 at 48 KB LDS =
// 3 blocks/CU: co-resident INDEPENDENT blocks overlap each other's barrier
// drains (m114 co-scheduling). This kernel = that shape + the pieces it
// lacked: 3-buffer counted-vmcnt rotation (R8, proven race-free), T2
// both-sides swizzle (R8: conflicts 12.6M -> 0), setprio.
// Per K-tile: 4 loads/thread stage, vmcnt(4) (tile t landed, t+1 in
// flight — never drain-0 mid-loop), 1 barrier, 8 ds_read_b128 + 16 MFMA.
// Buffer b=t%3 overwritten at iter t+1 only after that iter's barrier,
// which all waves reach after compute(t) — WAR-safe.
// launch_bounds(256,3): 12 waves/CU target, VGPR cap 170 (live ~120).
template <int EPI>
__global__ __launch_bounds__(256, 3) void k_gemm(
    const u16* __restrict__ A, const u16* __restrict__ BT,
    const float* __restrict__ bias,
    u16* __restrict__ Qo, u16* __restrict__ Ko, u16* __restrict__ Vo,
    float* __restrict__ Cout, int M, int N, int K) {
  __shared__ alignas(16) u16 AS[3][128 * 32];  // 3 x 8 KB
  __shared__ alignas(16) u16 BS[3][128 * 32];  // 3 x 8 KB
  const int wave = threadIdx.x >> 6, lane = threadIdx.x & 63;
  const int wr = wave >> 1, wc = wave & 1;
  const int l15 = lane & 15, l4 = lane >> 4;
  // staging geometry: 1KB chunk = 16 rows x 32 cols; lane l -> row-in-chunk
  // l>>2, 16B slot l&3; source slot pre-XORed with row&3 (T2 both-sides).
  const int srow = lane >> 2;
  const int sslot = (lane & 3) ^ (srow & 3);

  const int nwg = gridDim.x;  // 1536 / 512, both % 8 == 0
  const int swz = ((int)blockIdx.x & 7) * (nwg >> 3) + ((int)blockIdx.x >> 3);
  const int mt = M >> 7;
  const int bm = swz % mt, bn = swz / mt;
  const int brow = bm * 128, bcol = bn * 128;
  const int NT = K >> 5;

  const u16* aBase = A + (long)(brow + wave * 16 + srow) * K + sslot * 8;
  const u16* bBase = BT + (long)(bcol + wave * 16 + srow) * K + sslot * 8;
  const long K64 = (long)K * 64;  // 64-row advance

  auto stage = [&](int t, int buf) {  // 4 global_load_lds dwordx4 / thread
    const long t32 = (long)t * 32;
    __builtin_amdgcn_global_load_lds(GAS(aBase + t32),
                                     LAS(&AS[buf][wave * 512]), 16, 0, 0);
    __builtin_amdgcn_global_load_lds(GAS(aBase + t32 + K64),
                                     LAS(&AS[buf][(wave + 4) * 512]), 16, 0, 0);
    __builtin_amdgcn_global_load_lds(GAS(bBase + t32),
                                     LAS(&BS[buf][wave * 512]), 16, 0, 0);
    __builtin_amdgcn_global_load_lds(GAS(bBase + t32 + K64),
                                     LAS(&BS[buf][(wave + 4) * 512]), 16, 0, 0);
  };

  const f32x4 fzero = {0.f, 0.f, 0.f, 0.f};
  f32x4 acc[4][4];
#pragma unroll
  for (int m = 0; m < 4; ++m)
#pragma unroll
    for (int n = 0; n < 4; ++n) acc[m][n] = fzero;

  auto compute = [&](int buf) {
    const u16* Ac = &AS[buf][0];
    const u16* Bc = &BS[buf][0];
    bf16x8 afr[4], bfr[4];
#pragma unroll
    for (int f = 0; f < 4; ++f) {
      const int Ra = wr * 64 + f * 16 + l15;
      afr[f] = *(const bf16x8*)(Ac + Ra * 32 + ((l4 ^ (l15 & 3)) * 8));
      const int Rb = wc * 64 + f * 16 + l15;
      bfr[f] = *(const bf16x8*)(Bc + Rb * 32 + ((l4 ^ (l15 & 3)) * 8));
    }
    __builtin_amdgcn_s_setprio(1);
#pragma unroll
    for (int m = 0; m < 4; ++m)
#pragma unroll
      for (int n = 0; n < 4; ++n)
        acc[m][n] = __builtin_amdgcn_mfma_f32_16x16x32_bf16(afr[m], bfr[n],
                                                            acc[m][n], 0, 0, 0);
    __builtin_amdgcn_s_setprio(0);
  };

  stage(0, 0);
  stage(1, 1);
  int bufc = 0;
  for (int t = 0; t < NT - 1; ++t) {
    asm volatile("s_waitcnt vmcnt(4)" ::: "memory");  // tile t landed; t+1 flying
    __builtin_amdgcn_s_barrier();
    if (t + 2 < NT) {
      int bufn = bufc + 2;
      if (bufn >= 3) bufn -= 3;
      stage(t + 2, bufn);
    }
    compute(bufc);
    ++bufc;
    if (bufc == 3) bufc = 0;
  }
  asm volatile("s_waitcnt vmcnt(0)" ::: "memory");  // last tile
  __builtin_amdgcn_s_barrier();
  compute(bufc);

  if (EPI == 0) {
    // 128-col tiles never straddle the 2048 Q/K/V boundaries
    const int which = bcol >> 11;
    u16* dst = (which == 0) ? Qo : (which == 1) ? Ko : Vo;
    const int cbase = bcol & 2047;
#pragma unroll
    for (int n = 0; n < 4; ++n) {
      const int col = cbase + wc * 64 + n * 16 + l15;
      const int h = col >> 7, d = col & 127;
      const float bv = bias[bcol + wc * 64 + n * 16 + l15];
#pragma unroll
      for (int m = 0; m < 4; ++m) {
#pragma unroll
        for (int r = 0; r < 4; ++r) {
          const int row = brow + wr * 64 + m * 16 + l4 * 4 + r;  // b*2048+s
          const int bb = row >> 11, s = row & 2047;
          dst[(((long)(bb * 16 + h)) * 2048 + s) * 128 + d] =
              f32_to_bf16(acc[m][n][r] + bv);
        }
      }
    }
  } else {
#pragma unroll
    for (int m = 0; m < 4; ++m)
#pragma unroll
      for (int r = 0; r < 4; ++r) {
        const int row = brow + wr * 64 + m * 16 + l4 * 4 + r;
#pragma unroll
        for (int n = 0; n < 4; ++n) {
          const int col = bcol + wc * 64 + n * 16 + l15;
          Cout[(long)row * N + col] = acc[m][n][r] + bias[col];
        }
      }
  }
}

// ---------------- flash attention with ALiBi, causal ----------------
// (unchanged from R7 — verified; LDS-staged K/V^T, double-buffered, swizzled)
__global__ __launch_bounds__(256, 4) void k_attn(const u16* __restrict__ Q,
                                                 const u16* __restrict__ Kp,
                                                 const u16* __restrict__ VT,
                                                 u16* __restrict__ Oa) {
  __shared__ alignas(16) u16 Kl[2][64 * 128];
  __shared__ alignas(16) u16 Vl[2][128 * 64];
  __shared__ alignas(16) u16 Pl[4][16 * 64];
  const int b = blockIdx.x;
  const int bh = b & 31;
  const int qt = 31 - (b >> 5);  // heavy-first
  const int bb = bh >> 4, h = bh & 15;
  const int wave = threadIdx.x >> 6, lane = threadIdx.x & 63;
  const int l15 = lane & 15, l4 = lane >> 4;
  const int l7 = lane & 7, l8 = lane >> 3;
  const float LOG2E = 1.4426950408889634f;
  const float scale = 0.08838834764831845f * LOG2E;
  const float slope = exp2f(-0.5f * (float)h) * LOG2E;

  const int q0 = qt * 64 + wave * 16;
  const u16* Qb = Q + ((long)bh * 2048 + q0 + l15) * 128;
  bf16x8 qf[4];
#pragma unroll
  for (int kk = 0; kk < 4; ++kk) qf[kk] = *(const bf16x8*)(Qb + kk * 32 + l4 * 8);

  const u16* Kb = Kp + (long)bh * 2048 * 128;
  const u16* VTb = VT + (long)bh * 128 * 2048;

  auto stageK = [&](int jt, int buf) {
#pragma unroll
    for (int g = 0; g < 4; ++g) {
      const int wcc = g * 4 + wave;
      const int row = wcc * 4 + l4;
      const u16* src = Kb + (long)(jt * 64 + row) * 128 + ((l15 ^ (row & 7)) * 8);
      __builtin_amdgcn_global_load_lds(GAS(src), LAS(&Kl[buf][wcc * 512]), 16, 0, 0);
    }
  };
  auto stageV = [&](int jt, int buf) {
#pragma unroll
    for (int g = 0; g < 4; ++g) {
      const int wcc = g * 4 + wave;
      const int d = wcc * 8 + l8;
      const u16* src = VTb + (long)d * 2048 + jt * 64 + ((l7 ^ l8) * 8);
      __builtin_amdgcn_global_load_lds(GAS(src), LAS(&Vl[buf][wcc * 512]), 16, 0, 0);
    }
  };

  float rs[4];
  f32x4 O[8];
  const f32x4 fzero = {0.f, 0.f, 0.f, 0.f};
#pragma unroll
  for (int r = 0; r < 4; ++r) rs[r] = 0.f;
#pragma unroll
  for (int nb = 0; nb < 8; ++nb) O[nb] = fzero;

  u16* Pw = Pl[wave];
  const int irow = q0 + l4 * 4;
  const int sw = l15 & 7;

  stageK(0, 0);
  stageV(0, 0);
  __syncthreads();

  for (int jt = 0; jt <= qt; ++jt) {
    const int cur = jt & 1;
    if (jt < qt) {
      stageK(jt + 1, cur ^ 1);
      stageV(jt + 1, cur ^ 1);
    }
    const u16* Kc = Kl[cur];
    const u16* Vc = Vl[cur];
    const int j0 = jt * 64;
#pragma unroll
    for (int cb = 0; cb < 4; ++cb) {
      f32x4 sa = fzero;
      const u16* kp = Kc + (cb * 16 + l15) * 128;
#pragma unroll
      for (int kk = 0; kk < 4; ++kk) {
        bf16x8 kf = *(const bf16x8*)(kp + (((kk * 4 + l4) ^ sw) * 8));
        sa = __builtin_amdgcn_mfma_f32_16x16x32_bf16(qf[kk], kf, sa, 0, 0, 0);
      }
      const int j = j0 + cb * 16 + l15;
#pragma unroll
      for (int r = 0; r < 4; ++r) {
        int i = irow + r;
        float s = sa[r] * scale - slope * (float)(i - j);
        float p = __builtin_amdgcn_exp2f((j <= i) ? s : -1e30f);
        rs[r] += p;
        int rloc = l4 * 4 + r;
        int cbyte = (cb * 16 + l15) * 2;
        *(u16*)((char*)Pw + rloc * 128 + (cbyte ^ ((rloc & 7) << 4))) =
            f32_to_bf16(p);
      }
    }
    bf16x8 pf0 = *(const bf16x8*)((char*)Pw + l15 * 128 +
                                  ((l4 * 16) ^ ((l15 & 7) << 4)));
    bf16x8 pf1 = *(const bf16x8*)((char*)Pw + l15 * 128 +
                                  ((64 + l4 * 16) ^ ((l15 & 7) << 4)));
#pragma unroll
    for (int nb = 0; nb < 8; ++nb) {
      const u16* vp = Vc + (nb * 16 + l15) * 64;
      bf16x8 v0 = *(const bf16x8*)(vp + ((l4 ^ sw) * 8));
      bf16x8 v1 = *(const bf16x8*)(vp + (((4 + l4) ^ sw) * 8));
      O[nb] = __builtin_amdgcn_mfma_f32_16x16x32_bf16(pf0, v0, O[nb], 0, 0, 0);
      O[nb] = __builtin_amdgcn_mfma_f32_16x16x32_bf16(pf1, v1, O[nb], 0, 0, 0);
    }
    __syncthreads();
  }
#pragma unroll
  for (int r = 0; r < 4; ++r) {
    float v = rs[r];
    v += __shfl_xor(v, 1);
    v += __shfl_xor(v, 2);
    v += __shfl_xor(v, 4);
    v += __shfl_xor(v, 8);
    float inv = 1.f / v;
    int i = irow + r;
    u16* op = Oa + ((long)bb * 2048 + i) * 2048 + h * 128;
#pragma unroll
    for (int nb = 0; nb < 8; ++nb) op[nb * 16 + l15] = f32_to_bf16(O[nb][r] * inv);
  }
}

extern "C" void kernel_launch(void* const* d_in, const int* in_sizes, int n_in,
                              void* d_out, int out_size, void* d_ws, size_t ws_size,
                              hipStream_t stream) {
  const float* x = (const float*)d_in[0];
  const float* Wqkv = (const float*)d_in[1];
  const float* bqkv = (const float*)d_in[2];
  const float* Wo = (const float*)d_in[3];
  const float* bo = (const float*)d_in[4];
  float* out = (float*)d_out;

  char* ws = (char*)d_ws;
  u16* xb = (u16*)(ws);
  u16* VTb = (u16*)(ws);  // aliases xb (xb dead after GEMM1)
  u16* WqkvT = (u16*)(ws + 16777216);
  u16* attn_out = (u16*)(ws + 16777216);  // aliases WqkvT (dead after GEMM1)
  u16* WoT = (u16*)(ws + 16777216 + 25165824);
  u16* Qb = (u16*)(ws + 50331648);
  u16* Kb = (u16*)(ws + 67108864);
  u16* Vb = (u16*)(ws + 83886080);

  k_convert<<<8192, 256, 0, stream>>>(x, xb, 8388608 / 4);
  k_transpose_w<<<dim3(192, 64), 256, 0, stream>>>(Wqkv, WqkvT, 2048, 6144);
  k_transpose_w<<<dim3(64, 64), 256, 0, stream>>>(Wo, WoT, 2048, 2048);
  // GEMM1: 128^2 tiles -> 32 x 48 = 1536 blocks (6/CU work, 3 resident/CU)
  k_gemm<0><<<dim3(1536), 256, 0, stream>>>(xb, WqkvT, bqkv, Qb, Kb, Vb,
                                            nullptr, 4096, 6144, 2048);
  k_transpose_v<<<dim3(64, 4, 32), 256, 0, stream>>>(Vb, VTb);
  k_attn<<<dim3(1024), 256, 0, stream>>>(Qb, Kb, VTb, attn_out);
  // GEMM2: 128^2 tiles -> 32 x 16 = 512 blocks (2/CU work, all resident)
  k_gemm<1><<<dim3(512), 256, 0, stream>>>(attn_out, WoT, bo, nullptr,
                                           nullptr, nullptr, out, 4096, 2048,
                                           2048);
}

// Round 15
// 271.211 us; speedup vs baseline: 1.1077x; 1.0146x over previous
//
#include <hip/hip_runtime.h>

typedef __attribute__((ext_vector_type(4))) float f32x4;
typedef __attribute__((ext_vector_type(8))) __bf16 bf16x8;
typedef unsigned short u16;

#define GAS(p) ((const __attribute__((address_space(1))) void*)(p))
#define LAS(p) ((__attribute__((address_space(3))) void*)(p))

__device__ __forceinline__ u16 f32_to_bf16(float f) {
  unsigned u = __builtin_bit_cast(unsigned, f);
  u += 0x7FFFu + ((u >> 16) & 1u);
  return (u16)(u >> 16);
}

// ---------------- elementwise f32 -> bf16 ----------------
__global__ __launch_bounds__(256) void k_convert(const float* __restrict__ X,
                                                 u16* __restrict__ Y, int n4) {
  int i = blockIdx.x * 256 + threadIdx.x;
  if (i >= n4) return;
  float4 v = ((const float4*)X)[i];
  ushort4 r;
  r.x = f32_to_bf16(v.x); r.y = f32_to_bf16(v.y);
  r.z = f32_to_bf16(v.z); r.w = f32_to_bf16(v.w);
  ((ushort4*)Y)[i] = r;
}

// ---------------- W [K][N] f32 -> WT [N][K] bf16 ----------------
__global__ __launch_bounds__(256) void k_transpose_w(const float* __restrict__ W,
                                                     u16* __restrict__ WT,
                                                     int K, int N) {
  __shared__ float tile[32][33];
  int n0 = blockIdx.x * 32, k0 = blockIdx.y * 32;
  int tx = threadIdx.x & 31, ty = threadIdx.x >> 5;
#pragma unroll
  for (int r = 0; r < 4; ++r)
    tile[ty + r * 8][tx] = W[(long)(k0 + ty + r * 8) * N + n0 + tx];
  __syncthreads();
#pragma unroll
  for (int r = 0; r < 4; ++r)
    WT[(long)(n0 + ty + r * 8) * K + k0 + tx] = f32_to_bf16(tile[tx][ty + r * 8]);
}

// ---------------- V [BH][S][128] bf16 -> VT [BH][128][S] bf16 ----------------
__global__ __launch_bounds__(256) void k_transpose_v(const u16* __restrict__ V,
                                                     u16* __restrict__ VT) {
  __shared__ u16 tile[32][34];
  int s0 = blockIdx.x * 32, d0 = blockIdx.y * 32, bh = blockIdx.z;
  int tx = threadIdx.x & 31, ty = threadIdx.x >> 5;
  const u16* Vb = V + (long)bh * 2048 * 128;
  u16* VTb = VT + (long)bh * 128 * 2048;
#pragma unroll
  for (int r = 0; r < 4; ++r)
    tile[ty + r * 8][tx] = Vb[(long)(s0 + ty + r * 8) * 128 + d0 + tx];
  __syncthreads();
#pragma unroll
  for (int r = 0; r < 4; ++r)
    VTb[(long)(d0 + ty + r * 8) * 2048 + s0 + tx] = tile[tx][ty + r * 8];
}

// ===== 128x128 bf16 GEMM, BK=32, 3 LDS buffers, 4 waves, 3 BLOCKS/CU =====
// R14 structure (best measured: cross-block barrier-drain overlap at 3
// blocks/CU + 3-buffer counted-vmcnt(4) + setprio) with ONE fix:
// R14's swizzle key (row&3) left a 4-way bank conflict (12.6M/dispatch).
// At BK=32 a row is 64 B = 16 banks; start-bank = (16*row + 4*slot) % 32.
// Correct key: slot ^= (row>>1)&3 — over each 16-lane group the 8 even-l15
// lanes cycle slots {0..3} twice (start banks {0,4,8,12} x2) and odd-l15
// likewise ({16,20,24,28} x2) -> 2 lanes/bank = free (m136).
// Write side (linear LDS dest): source slot = (lane&3) ^ ((srow>>1)&3);
// read side: slot = l4 ^ ((l15>>1)&3). Same involution both sides (#21).
template <int EPI>
__global__ __launch_bounds__(256, 3) void k_gemm(
    const u16* __restrict__ A, const u16* __restrict__ BT,
    const float* __restrict__ bias,
    u16* __restrict__ Qo, u16* __restrict__ Ko, u16* __restrict__ Vo,
    float* __restrict__ Cout, int M, int N, int K) {
  __shared__ alignas(16) u16 AS[3][128 * 32];  // 3 x 8 KB
  __shared__ alignas(16) u16 BS[3][128 * 32];  // 3 x 8 KB
  const int wave = threadIdx.x >> 6, lane = threadIdx.x & 63;
  const int wr = wave >> 1, wc = wave & 1;
  const int l15 = lane & 15, l4 = lane >> 4;
  // staging: 1KB chunk = 16 rows x 32 cols; lane -> row lane>>2, slot lane&3;
  // source slot pre-XORed with (row>>1)&3 (T2 both-sides, R15 fix).
  const int srow = lane >> 2;
  const int sslot = (lane & 3) ^ ((srow >> 1) & 3);

  const int nwg = gridDim.x;  // 1536 / 512, both % 8 == 0
  const int swz = ((int)blockIdx.x & 7) * (nwg >> 3) + ((int)blockIdx.x >> 3);
  const int mt = M >> 7;
  const int bm = swz % mt, bn = swz / mt;
  const int brow = bm * 128, bcol = bn * 128;
  const int NT = K >> 5;

  const u16* aBase = A + (long)(brow + wave * 16 + srow) * K + sslot * 8;
  const u16* bBase = BT + (long)(bcol + wave * 16 + srow) * K + sslot * 8;
  const long K64 = (long)K * 64;  // 64-row advance

  auto stage = [&](int t, int buf) {  // 4 global_load_lds dwordx4 / thread
    const long t32 = (long)t * 32;
    __builtin_amdgcn_global_load_lds(GAS(aBase + t32),
                                     LAS(&AS[buf][wave * 512]), 16, 0, 0);
    __builtin_amdgcn_global_load_lds(GAS(aBase + t32 + K64),
                                     LAS(&AS[buf][(wave + 4) * 512]), 16, 0, 0);
    __builtin_amdgcn_global_load_lds(GAS(bBase + t32),
                                     LAS(&BS[buf][wave * 512]), 16, 0, 0);
    __builtin_amdgcn_global_load_lds(GAS(bBase + t32 + K64),
                                     LAS(&BS[buf][(wave + 4) * 512]), 16, 0, 0);
  };

  const f32x4 fzero = {0.f, 0.f, 0.f, 0.f};
  f32x4 acc[4][4];
#pragma unroll
  for (int m = 0; m < 4; ++m)
#pragma unroll
    for (int n = 0; n < 4; ++n) acc[m][n] = fzero;

  const int rkey = (l15 >> 1) & 3;  // read-side XOR key: (row>>1)&3 per lane
  auto compute = [&](int buf) {
    const u16* Ac = &AS[buf][0];
    const u16* Bc = &BS[buf][0];
    bf16x8 afr[4], bfr[4];
#pragma unroll
    for (int f = 0; f < 4; ++f) {
      const int Ra = wr * 64 + f * 16 + l15;
      afr[f] = *(const bf16x8*)(Ac + Ra * 32 + ((l4 ^ rkey) * 8));
      const int Rb = wc * 64 + f * 16 + l15;
      bfr[f] = *(const bf16x8*)(Bc + Rb * 32 + ((l4 ^ rkey) * 8));
    }
    __builtin_amdgcn_s_setprio(1);
#pragma unroll
    for (int m = 0; m < 4; ++m)
#pragma unroll
      for (int n = 0; n < 4; ++n)
        acc[m][n] = __builtin_amdgcn_mfma_f32_16x16x32_bf16(afr[m], bfr[n],
                                                            acc[m][n], 0, 0, 0);
    __builtin_amdgcn_s_setprio(0);
  };

  stage(0, 0);
  stage(1, 1);
  int bufc = 0;
  for (int t = 0; t < NT - 1; ++t) {
    asm volatile("s_waitcnt vmcnt(4)" ::: "memory");  // tile t landed; t+1 flying
    __builtin_amdgcn_s_barrier();
    if (t + 2 < NT) {
      int bufn = bufc + 2;
      if (bufn >= 3) bufn -= 3;
      stage(t + 2, bufn);
    }
    compute(bufc);
    ++bufc;
    if (bufc == 3) bufc = 0;
  }
  asm volatile("s_waitcnt vmcnt(0)" ::: "memory");  // last tile
  __builtin_amdgcn_s_barrier();
  compute(bufc);

  if (EPI == 0) {
    // 128-col tiles never straddle the 2048 Q/K/V boundaries
    const int which = bcol >> 11;
    u16* dst = (which == 0) ? Qo : (which == 1) ? Ko : Vo;
    const int cbase = bcol & 2047;
#pragma unroll
    for (int n = 0; n < 4; ++n) {
      const int col = cbase + wc * 64 + n * 16 + l15;
      const int h = col >> 7, d = col & 127;
      const float bv = bias[bcol + wc * 64 + n * 16 + l15];
#pragma unroll
      for (int m = 0; m < 4; ++m) {
#pragma unroll
        for (int r = 0; r < 4; ++r) {
          const int row = brow + wr * 64 + m * 16 + l4 * 4 + r;  // b*2048+s
          const int bb = row >> 11, s = row & 2047;
          dst[(((long)(bb * 16 + h)) * 2048 + s) * 128 + d] =
              f32_to_bf16(acc[m][n][r] + bv);
        }
      }
    }
  } else {
#pragma unroll
    for (int m = 0; m < 4; ++m)
#pragma unroll
      for (int r = 0; r < 4; ++r) {
        const int row = brow + wr * 64 + m * 16 + l4 * 4 + r;
#pragma unroll
        for (int n = 0; n < 4; ++n) {
          const int col = bcol + wc * 64 + n * 16 + l15;
          Cout[(long)row * N + col] = acc[m][n][r] + bias[col];
        }
      }
  }
}

// ---------------- flash attention with ALiBi, causal ----------------
// (unchanged from R7 — verified; LDS-staged K/V^T, double-buffered, swizzled)
__global__ __launch_bounds__(256, 4) void k_attn(const u16* __restrict__ Q,
                                                 const u16* __restrict__ Kp,
                                                 const u16* __restrict__ VT,
                                                 u16* __restrict__ Oa) {
  __shared__ alignas(16) u16 Kl[2][64 * 128];
  __shared__ alignas(16) u16 Vl[2][128 * 64];
  __shared__ alignas(16) u16 Pl[4][16 * 64];
  const int b = blockIdx.x;
  const int bh = b & 31;
  const int qt = 31 - (b >> 5);  // heavy-first
  const int bb = bh >> 4, h = bh & 15;
  const int wave = threadIdx.x >> 6, lane = threadIdx.x & 63;
  const int l15 = lane & 15, l4 = lane >> 4;
  const int l7 = lane & 7, l8 = lane >> 3;
  const float LOG2E = 1.4426950408889634f;
  const float scale = 0.08838834764831845f * LOG2E;
  const float slope = exp2f(-0.5f * (float)h) * LOG2E;

  const int q0 = qt * 64 + wave * 16;
  const u16* Qb = Q + ((long)bh * 2048 + q0 + l15) * 128;
  bf16x8 qf[4];
#pragma unroll
  for (int kk = 0; kk < 4; ++kk) qf[kk] = *(const bf16x8*)(Qb + kk * 32 + l4 * 8);

  const u16* Kb = Kp + (long)bh * 2048 * 128;
  const u16* VTb = VT + (long)bh * 128 * 2048;

  auto stageK = [&](int jt, int buf) {
#pragma unroll
    for (int g = 0; g < 4; ++g) {
      const int wcc = g * 4 + wave;
      const int row = wcc * 4 + l4;
      const u16* src = Kb + (long)(jt * 64 + row) * 128 + ((l15 ^ (row & 7)) * 8);
      __builtin_amdgcn_global_load_lds(GAS(src), LAS(&Kl[buf][wcc * 512]), 16, 0, 0);
    }
  };
  auto stageV = [&](int jt, int buf) {
#pragma unroll
    for (int g = 0; g < 4; ++g) {
      const int wcc = g * 4 + wave;
      const int d = wcc * 8 + l8;
      const u16* src = VTb + (long)d * 2048 + jt * 64 + ((l7 ^ l8) * 8);
      __builtin_amdgcn_global_load_lds(GAS(src), LAS(&Vl[buf][wcc * 512]), 16, 0, 0);
    }
  };

  float rs[4];
  f32x4 O[8];
  const f32x4 fzero = {0.f, 0.f, 0.f, 0.f};
#pragma unroll
  for (int r = 0; r < 4; ++r) rs[r] = 0.f;
#pragma unroll
  for (int nb = 0; nb < 8; ++nb) O[nb] = fzero;

  u16* Pw = Pl[wave];
  const int irow = q0 + l4 * 4;
  const int sw = l15 & 7;

  stageK(0, 0);
  stageV(0, 0);
  __syncthreads();

  for (int jt = 0; jt <= qt; ++jt) {
    const int cur = jt & 1;
    if (jt < qt) {
      stageK(jt + 1, cur ^ 1);
      stageV(jt + 1, cur ^ 1);
    }
    const u16* Kc = Kl[cur];
    const u16* Vc = Vl[cur];
    const int j0 = jt * 64;
#pragma unroll
    for (int cb = 0; cb < 4; ++cb) {
      f32x4 sa = fzero;
      const u16* kp = Kc + (cb * 16 + l15) * 128;
#pragma unroll
      for (int kk = 0; kk < 4; ++kk) {
        bf16x8 kf = *(const bf16x8*)(kp + (((kk * 4 + l4) ^ sw) * 8));
        sa = __builtin_amdgcn_mfma_f32_16x16x32_bf16(qf[kk], kf, sa, 0, 0, 0);
      }
      const int j = j0 + cb * 16 + l15;
#pragma unroll
      for (int r = 0; r < 4; ++r) {
        int i = irow + r;
        float s = sa[r] * scale - slope * (float)(i - j);
        float p = __builtin_amdgcn_exp2f((j <= i) ? s : -1e30f);
        rs[r] += p;
        int rloc = l4 * 4 + r;
        int cbyte = (cb * 16 + l15) * 2;
        *(u16*)((char*)Pw + rloc * 128 + (cbyte ^ ((rloc & 7) << 4))) =
            f32_to_bf16(p);
      }
    }
    bf16x8 pf0 = *(const bf16x8*)((char*)Pw + l15 * 128 +
                                  ((l4 * 16) ^ ((l15 & 7) << 4)));
    bf16x8 pf1 = *(const bf16x8*)((char*)Pw + l15 * 128 +
                                  ((64 + l4 * 16) ^ ((l15 & 7) << 4)));
#pragma unroll
    for (int nb = 0; nb < 8; ++nb) {
      const u16* vp = Vc + (nb * 16 + l15) * 64;
      bf16x8 v0 = *(const bf16x8*)(vp + ((l4 ^ sw) * 8));
      bf16x8 v1 = *(const bf16x8*)(vp + (((4 + l4) ^ sw) * 8));
      O[nb] = __builtin_amdgcn_mfma_f32_16x16x32_bf16(pf0, v0, O[nb], 0, 0, 0);
      O[nb] = __builtin_amdgcn_mfma_f32_16x16x32_bf16(pf1, v1, O[nb], 0, 0, 0);
    }
    __syncthreads();
  }
#pragma unroll
  for (int r = 0; r < 4; ++r) {
    float v = rs[r];
    v += __shfl_xor(v, 1);
    v += __shfl_xor(v, 2);
    v += __shfl_xor(v, 4);
    v += __shfl_xor(v, 8);
    float inv = 1.f / v;
    int i = irow + r;
    u16* op = Oa + ((long)bb * 2048 + i) * 2048 + h * 128;
#pragma unroll
    for (int nb = 0; nb < 8; ++nb) op[nb * 16 + l15] = f32_to_bf16(O[nb][r] * inv);
  }
}

extern "C" void kernel_launch(void* const* d_in, const int* in_sizes, int n_in,
                              void* d_out, int out_size, void* d_ws, size_t ws_size,
                              hipStream_t stream) {
  const float* x = (const float*)d_in[0];
  const float* Wqkv = (const float*)d_in[1];
  const float* bqkv = (const float*)d_in[2];
  const float* Wo = (const float*)d_in[3];
  const float* bo = (const float*)d_in[4];
  float* out = (float*)d_out;

  char* ws = (char*)d_ws;
  u16* xb = (u16*)(ws);
  u16* VTb = (u16*)(ws);  // aliases xb (xb dead after GEMM1)
  u16* WqkvT = (u16*)(ws + 16777216);
  u16* attn_out = (u16*)(ws + 16777216);  // aliases WqkvT (dead after GEMM1)
  u16* WoT = (u16*)(ws + 16777216 + 25165824);
  u16* Qb = (u16*)(ws + 50331648);
  u16* Kb = (u16*)(ws + 67108864);
  u16* Vb = (u16*)(ws + 83886080);

  k_convert<<<8192, 256, 0, stream>>>(x, xb, 8388608 / 4);
  k_transpose_w<<<dim3(192, 64), 256, 0, stream>>>(Wqkv, WqkvT, 2048, 6144);
  k_transpose_w<<<dim3(64, 64), 256, 0, stream>>>(Wo, WoT, 2048, 2048);
  // GEMM1: 128^2 tiles -> 32 x 48 = 1536 blocks (6/CU work, 3 resident/CU)
  k_gemm<0><<<dim3(1536), 256, 0, stream>>>(xb, WqkvT, bqkv, Qb, Kb, Vb,
                                            nullptr, 4096, 6144, 2048);
  k_transpose_v<<<dim3(64, 4, 32), 256, 0, stream>>>(Vb, VTb);
  k_attn<<<dim3(1024), 256, 0, stream>>>(Qb, Kb, VTb, attn_out);
  // GEMM2: 128^2 tiles -> 32 x 16 = 512 blocks (2/CU work, all resident)
  k_gemm<1><<<dim3(512), 256, 0, stream>>>(attn_out, WoT, bo, nullptr,
                                           nullptr, nullptr, out, 4096, 2048,
                                           2048);
}